// Round 4
// baseline (150.878 us; speedup 1.0000x reference)
//
#include <hip/hip_runtime.h>
#include <math.h>

// Problem constants (from reference setup_inputs)
#define BS 32
#define CH 3
#define HH 512
#define WW 512
#define HWSZ (HH * WW)          // 262144
#define MOMENTUM 0.8
#define EPSILON 1e-5

// ---------------- stats kernel ----------------
// S1[c] = sum_b x[b,c,0,0]
// S2[c] = sum_{b,h,w} x^2
// S3[c] = sum_{b,h,w} x[h,w] * x[(-h)%H, (-w)%W]
//
// Row-mirror symmetry: rowsum(h) == rowsum((H-h)%H), where
//   rowsum(h) = sum_w x[h,w]*x[(H-h)%H,(W-w)%W].
// So S3 = rowsum(0) + rowsum(256) + 2*sum_{h=1}^{255} rowsum(h).
// Each block owns A-rows [q*8, q*8+8) (q=32 -> just row 256), stages the
// mirror rows in LDS (read once, forward, aligned), and every element of x
// is fetched from global exactly once across the whole grid.

constexpr int RPC = 8;       // A-rows per chunk
constexpr int CHUNKS = 33;   // q=0..31 cover rows 0..255; q=32 covers row 256

__global__ __launch_bounds__(256) void stats_kernel(
    const float* __restrict__ x, double* __restrict__ sums) {
    const int plane = blockIdx.x / CHUNKS;   // 0..95 = b*3+c
    const int q     = blockIdx.x % CHUNKS;
    const int c     = plane % CH;
    const float* __restrict__ base = x + (size_t)plane * HWSZ;
    const int tid = threadIdx.x;
    const int i   = tid >> 5;        // row slot 0..7
    const int wl  = tid & 31;        // 32 threads per row
    const int nrows = (q == 32) ? 1 : RPC;
    const int r0 = q * RPC;
    const int h  = r0 + i;
    const bool active = (i < nrows);

    __shared__ float ldsB[RPC][WW];  // mirror rows, stored forward (16 KiB)

    float s1 = 0.f, s2 = 0.f, s3 = 0.f;
    float4 av[4];

    if (active) {
        const float* __restrict__ arow = base + h * WW;
        const int brow = (HH - h) & (HH - 1);
        const float* __restrict__ brp = base + brow * WW;
        const bool count_b = (brow > 256);   // avoid double-counting s2
#pragma unroll
        for (int k = 0; k < 4; ++k) {        // issue A loads early
            const int w = (wl + 32 * k) * 4;
            av[k] = *reinterpret_cast<const float4*>(arow + w);
        }
#pragma unroll
        for (int k = 0; k < 4; ++k) {        // stage mirror row
            const int w = (wl + 32 * k) * 4;
            const float4 b = *reinterpret_cast<const float4*>(brp + w);
            if (count_b) s2 += b.x * b.x + b.y * b.y + b.z * b.z + b.w * b.w;
            *reinterpret_cast<float4*>(&ldsB[i][w]) = b;
        }
    }
    __syncthreads();
    if (active) {
        const float fac = (h == 0 || h == 256) ? 1.f : 2.f;
        float s3l = 0.f;
#pragma unroll
        for (int k = 0; k < 4; ++k) {
            const int w = (wl + 32 * k) * 4;
            const float4 a = av[k];
            s2 += a.x * a.x + a.y * a.y + a.z * a.z + a.w * a.w;
            // partners of w..w+3 are (512-w),511-w,510-w,509-w  (mod 512)
            // = { q2.x, q1.w, q1.z, q1.y } from two ALIGNED lds float4s
            const float4 q1 = *reinterpret_cast<const float4*>(&ldsB[i][(508 - w) & (WW - 1)]);
            const float4 q2 = *reinterpret_cast<const float4*>(&ldsB[i][(512 - w) & (WW - 1)]);
            s3l += a.x * q2.x + a.y * q1.w + a.z * q1.z + a.w * q1.y;
            if (h == 0 && w == 0) s1 = a.x;   // x[b,c,0,0]
        }
        s3 = fac * s3l;
    }

    // wave (64-lane) shuffle reduce, then cross-wave via LDS
#pragma unroll
    for (int off = 32; off > 0; off >>= 1) {
        s1 += __shfl_down(s1, off);
        s2 += __shfl_down(s2, off);
        s3 += __shfl_down(s3, off);
    }
    __shared__ float red[3][4];
    const int lane = tid & 63, wv = tid >> 6;
    if (lane == 0) { red[0][wv] = s1; red[1][wv] = s2; red[2][wv] = s3; }
    __syncthreads();
    if (tid == 0) {
        double t1 = 0.0, t2 = 0.0, t3 = 0.0;
#pragma unroll
        for (int j = 0; j < 4; ++j) {
            t1 += (double)red[0][j];
            t2 += (double)red[1][j];
            t3 += (double)red[2][j];
        }
        atomicAdd(&sums[c * 3 + 0], t1);
        atomicAdd(&sums[c * 3 + 1], t2);
        atomicAdd(&sums[c * 3 + 2], t3);
    }
}

// ---------------- finalize: per-channel scale/shift ----------------
__global__ void finalize_kernel(const double* __restrict__ sums,
                                const float* __restrict__ gamma,
                                const float* __restrict__ beta,
                                const float* __restrict__ rmean,
                                const float* __restrict__ rvar,
                                float* __restrict__ ss) {
    const int c = threadIdx.x;
    if (c >= CH) return;
    const double S1 = sums[c * 3 + 0];
    const double S2 = sums[c * 3 + 1];
    const double S3 = sums[c * 3 + 2];
    const double N = (double)BS * (double)HWSZ;      // bs*H*W
    const double mean = S1 / N;
    const double ex2  = (S2 + S3) / (2.0 * N * (double)HWSZ);  // /(2*bs*H^2*W^2)
    const double var  = ex2 - mean * mean;
    const double rm = (double)rmean[c] * MOMENTUM + (1.0 - MOMENTUM) * mean;
    const double rv = (double)rvar[c]  * MOMENTUM + (1.0 - MOMENTUM) * var;
    const double inv_std = 1.0 / sqrt(rv + EPSILON);
    const float scale = (float)((double)gamma[c] * inv_std);
    const float shift = (float)((double)beta[c] - (double)scale * rm);
    ss[c * 2 + 0] = scale;
    ss[c * 2 + 1] = shift;
}

// ---------------- elementwise normalize ----------------
__global__ __launch_bounds__(256) void norm_kernel(
    const float* __restrict__ x, const float* __restrict__ ss,
    float* __restrict__ out) {
    float sc[CH], sh[CH];
#pragma unroll
    for (int c = 0; c < CH; ++c) { sc[c] = ss[c * 2]; sh[c] = ss[c * 2 + 1]; }
    const int n4 = BS * CH * HWSZ / 4;                // 6,291,456
    const int stride = gridDim.x * blockDim.x;
    for (int i4 = blockIdx.x * blockDim.x + threadIdx.x; i4 < n4; i4 += stride) {
        const int c = (i4 >> 16) % CH;                // 65536 f4 per plane
        const float4 v = reinterpret_cast<const float4*>(x)[i4];
        const float s = sc[c], t = sh[c];
        float4 o;
        o.x = fmaf(v.x, s, t);
        o.y = fmaf(v.y, s, t);
        o.z = fmaf(v.z, s, t);
        o.w = fmaf(v.w, s, t);
        reinterpret_cast<float4*>(out)[i4] = o;
    }
}

extern "C" void kernel_launch(void* const* d_in, const int* in_sizes, int n_in,
                              void* d_out, int out_size, void* d_ws, size_t ws_size,
                              hipStream_t stream) {
    const float* x     = (const float*)d_in[0];
    const float* gamma = (const float*)d_in[1];
    const float* beta  = (const float*)d_in[2];
    const float* rmean = (const float*)d_in[3];
    const float* rvar  = (const float*)d_in[4];
    float* out = (float*)d_out;

    double* sums = (double*)d_ws;                     // 9 doubles
    float*  ss   = (float*)((char*)d_ws + 128);       // 6 floats

    hipMemsetAsync(d_ws, 0, 160, stream);
    stats_kernel<<<BS * CH * CHUNKS, 256, 0, stream>>>(x, sums);
    finalize_kernel<<<1, 64, 0, stream>>>(sums, gamma, beta, rmean, rvar, ss);
    norm_kernel<<<2048, 256, 0, stream>>>(x, ss, out);
}